// Round 5
// baseline (280.001 us; speedup 1.0000x reference)
//
#include <hip/hip_runtime.h>
#include <stdint.h>

typedef unsigned long long u64;

#define N_ANCH   300000
#define N_CLS    80
#define DET_DIM  85
#define TOPK     1000
#define MAXB     300
#define NMS_THR  0.4f
#define CAP      4096
#define N4       (N_ANCH / 4)

#define NB_HIST  80     // 80*1024 = 81920 >= 75000 uint4 -> one element per thread
#define NB_RANK  96     // 1536 waves; one wave per candidate, stride loop
#define NB_MASK  250    // 4000 waves for 16000 mask words

// ws layout (uint32 units)
#define OFF_SBITS   0          // 300000 u32
#define OFF_HA      300032     // 4096 u32 global hist A
#define OFF_HB      304128     // 4096 u32 global hist B
#define OFF_META    308224     // 64 u32: [4]=cand cnt
#define OFF_CAND    308288     // 4096 u64 = 8192 u32 (byte %8==0)
#define OFF_TOPK    316480     // 1000 u32
#define OFF_BOXK    317480     // 1000 float4 (byte %16==0)
#define OFF_MASK    321480     // 16000 u64 (byte %8==0)

// ---------------- scores = max over 80 classes (pure BW pass, ~15 us roofline) ----------------
__global__ __launch_bounds__(256) void k_scores(const float4* __restrict__ cls4,
                                                uint32_t* __restrict__ sbits,
                                                uint32_t* __restrict__ ha,
                                                uint32_t* __restrict__ hb,
                                                uint32_t* __restrict__ meta) {
    int tid = threadIdx.x;
    if (blockIdx.x == 0) {                       // zero cross-kernel state (ws poisoned)
        if (tid == 0) meta[4] = 0;
        for (int i = tid; i < 4096; i += 256) { ha[i] = 0; hb[i] = 0; }
    }
    int wave = tid >> 6, lane = tid & 63, g = lane >> 2, q = lane & 3;
    int row = blockIdx.x * 64 + wave * 16 + g;
    if (row >= N_ANCH) return;
    const float4* rp = cls4 + (size_t)row * 20;  // 80 floats = 20 float4
    float m = -1.0f;
    #pragma unroll
    for (int k = 0; k < 5; k++) {
        float4 v = rp[q + k * 4];
        m = fmaxf(m, fmaxf(fmaxf(v.x, v.y), fmaxf(v.z, v.w)));
    }
    m = fmaxf(m, __shfl_xor(m, 1));
    m = fmaxf(m, __shfl_xor(m, 2));
    if (q == 0) sbits[row] = __float_as_uint(m); // scores >= 0: bit order == value order
}

// ballot-aggregated LDS histogram add (level-A distribution is degenerate:
// ~99% of maxes land in a handful of bits[31:20] bins -> ~1 atomic per wave).
__device__ __forceinline__ void agg_add(uint32_t* h, uint32_t bin, bool valid) {
    int lane = threadIdx.x & 63;
    bool done = !valid;
    while (true) {
        unsigned long long rem = __ballot(!done);
        if (rem == 0ull) break;
        int leader = __ffsll((long long)rem) - 1;
        uint32_t lbin = __shfl(bin, leader);
        bool mine = (!done) && (bin == lbin);
        unsigned long long grp = __ballot(mine);
        if (lane == leader) atomicAdd(&h[lbin], (uint32_t)__popcll(grp));
        done = done || mine;
    }
}

// block-wide (1024 thr) threshold find via shfl wave-scan:
// per-thread counts c[k] for bins 4095-(tid*4+k); find bin where descending-suffix
// count crosses K. res[0]=bin, res[1]=count strictly above. Ends synced.
__device__ __forceinline__ void findthr_core(const uint32_t c[4], uint32_t* wred,
                                             uint32_t K, uint32_t* res) {
    int tid = threadIdx.x, lane = tid & 63, wave = tid >> 6;
    uint32_t s = c[0] + c[1] + c[2] + c[3];
    uint32_t x = s;
    #pragma unroll
    for (int off = 1; off < 64; off <<= 1) {
        uint32_t v = __shfl_up(x, off);
        if (lane >= off) x += v;
    }
    if (lane == 63) wred[wave] = x;
    __syncthreads();
    if (wave == 0) {
        uint32_t w = (lane < 16) ? wred[lane] : 0u;
        #pragma unroll
        for (int off = 1; off < 16; off <<= 1) {
            uint32_t v = __shfl_up(w, off);
            if (lane >= off) w += v;
        }
        if (lane < 16) wred[lane] = w;
    }
    __syncthreads();
    uint32_t base = (wave == 0) ? 0u : wred[wave - 1];
    uint32_t incl = base + x, excl = incl - s;
    if (excl < K && incl >= K) {                 // exactly one thread matches
        uint32_t run = excl;
        #pragma unroll
        for (int k = 0; k < 4; k++) {
            uint32_t nr = run + c[k];
            if (run < K && nr >= K) { res[0] = 4095 - (tid * 4 + k); res[1] = run; }
            run = nr;
        }
    }
    __syncthreads();
}

// helper: load the 4 descending bins for this thread as one uint4
__device__ __forceinline__ void load_bins(const uint32_t* __restrict__ hist, uint32_t c[4]) {
    uint4 q = ((const uint4*)hist)[1023 - threadIdx.x];
    c[0] = q.w; c[1] = q.z; c[2] = q.y; c[3] = q.x;
}

// ---------------- level-A histogram (bits[31:20]) -> global ha, 1 elem/thread ----------------
__global__ __launch_bounds__(1024) void k_histA(const uint4* __restrict__ sb4,
                                                uint32_t* __restrict__ ha) {
    __shared__ uint32_t h[4096];
    int tid = threadIdx.x;
    for (int i = tid; i < 4096; i += 1024) h[i] = 0;
    __syncthreads();
    int t4 = blockIdx.x * 1024 + tid;
    bool v = t4 < N4;
    uint4 sv = v ? sb4[t4] : make_uint4(0, 0, 0, 0);
    agg_add(h, sv.x >> 20, v);
    agg_add(h, sv.y >> 20, v);
    agg_add(h, sv.z >> 20, v);
    agg_add(h, sv.w >> 20, v);
    __syncthreads();
    // flush: thread-distinct bins within a block -> contention only across 80 blocks
    for (int i = tid; i < 4096; i += 1024) { uint32_t c = h[i]; if (c) atomicAdd(&ha[i], c); }
}

// ------- level-B: redundant findthr(A) per block + conditioned hist on bits[19:8] -------
__global__ __launch_bounds__(1024) void k_histB(const uint4* __restrict__ sb4,
                                                const uint32_t* __restrict__ ha,
                                                uint32_t* __restrict__ hb) {
    __shared__ uint32_t h[4096];
    __shared__ uint32_t wred[16];
    __shared__ uint32_t mr[2];
    int tid = threadIdx.x;
    uint32_t c[4];
    load_bins(ha, c);
    findthr_core(c, wred, TOPK, mr);
    uint32_t binA = mr[0];
    for (int i = tid; i < 4096; i += 1024) h[i] = 0;
    __syncthreads();
    int t4 = blockIdx.x * 1024 + tid;
    if (t4 < N4) {
        uint4 sv = sb4[t4];
        if ((sv.x >> 20) == binA) atomicAdd(&h[(sv.x >> 8) & 0xFFFu], 1u);
        if ((sv.y >> 20) == binA) atomicAdd(&h[(sv.y >> 8) & 0xFFFu], 1u);
        if ((sv.z >> 20) == binA) atomicAdd(&h[(sv.z >> 8) & 0xFFFu], 1u);
        if ((sv.w >> 20) == binA) atomicAdd(&h[(sv.w >> 8) & 0xFFFu], 1u);
    }
    __syncthreads();
    for (int i = tid; i < 4096; i += 1024) { uint32_t v = h[i]; if (v) atomicAdd(&hb[i], v); }
}

// ------- compact: redundant findthr(A)+findthr(B), single-pass ballot compact -------
__global__ __launch_bounds__(1024) void k_compact(const uint4* __restrict__ sb4,
                                                  const uint32_t* __restrict__ ha,
                                                  const uint32_t* __restrict__ hb,
                                                  uint32_t* __restrict__ meta,
                                                  u64* __restrict__ cand) {
    __shared__ uint32_t wred[16];
    __shared__ uint32_t mr[2];
    int tid = threadIdx.x, lane = tid & 63;
    uint32_t c[4];
    load_bins(ha, c);
    findthr_core(c, wred, TOPK, mr);
    uint32_t binA = mr[0], GA = mr[1];
    load_bins(hb, c);
    findthr_core(c, wred, TOPK - GA, mr);
    uint32_t T24 = (binA << 12) | mr[0];
    int t4 = blockIdx.x * 1024 + tid;
    bool v = t4 < N4;
    uint4 sv = v ? sb4[t4] : make_uint4(0, 0, 0, 0);
    uint32_t sl[4] = {sv.x, sv.y, sv.z, sv.w};
    #pragma unroll
    for (int s = 0; s < 4; s++) {
        uint32_t sb = sl[s];
        bool m = v && ((sb >> 8) >= T24);
        unsigned long long b = __ballot(m);
        if (b) {                                  // wave-uniform; cand order irrelevant
            int leader = __ffsll((long long)b) - 1;
            uint32_t base2 = 0;
            if (lane == leader) base2 = atomicAdd(&meta[4], (uint32_t)__popcll(b));
            base2 = __shfl(base2, leader);
            if (m) {
                uint32_t p = base2 + (uint32_t)__popcll(b & ((1ull << lane) - 1ull));
                uint32_t idx = (uint32_t)(t4 * 4 + s);
                if (p < CAP) cand[p] = ((u64)sb << 32) | (uint32_t)(~idx);
            }
        }
    }
}

// ------- exact rank: LDS-staged candidates, ONE WAVE per candidate (lane-parallel) -------
__global__ __launch_bounds__(1024) void k_rank(const u64* __restrict__ cand,
                                               const uint32_t* __restrict__ meta,
                                               uint32_t* __restrict__ topk,
                                               const float4* __restrict__ boxes4,
                                               float4* __restrict__ boxk) {
    __shared__ u64 candS[CAP];
    int tid = threadIdx.x, wave = tid >> 6, lane = tid & 63;
    uint32_t C = meta[4]; if (C > CAP) C = CAP;
    uint32_t Cpad = (C + 63u) & ~63u;
    for (uint32_t t = tid; t < Cpad; t += 1024) candS[t] = (t < C) ? cand[t] : 0ull;
    __syncthreads();
    for (uint32_t i = (uint32_t)(blockIdx.x * 16 + wave); i < C; i += NB_RANK * 16) {
        u64 my = candS[i];
        uint32_t r = 0;
        for (uint32_t j0 = 0; j0 < Cpad; j0 += 64)
            r += (uint32_t)__popcll(__ballot(candS[j0 + lane] > my));  // 0-pad never > my
        if (r < TOPK && lane == 0) {              // keys unique -> all ranks 0..999 hit once
            uint32_t idx = ~(uint32_t)(my & 0xFFFFFFFFull);
            if (idx < N_ANCH) { topk[r] = idx; boxk[r] = boxes4[idx]; }
        }
    }
}

// ------- suppression bitmask M[i][w]: boxes + areas staged in LDS -------
__global__ __launch_bounds__(1024) void k_mask(const float4* __restrict__ boxk,
                                               u64* __restrict__ M) {
    __shared__ float4 bks[TOPK];
    __shared__ float areaS[TOPK];
    int tid = threadIdx.x, wave = tid >> 6, lane = tid & 63;
    for (int i = tid; i < TOPK; i += 1024) {
        float4 b = boxk[i];
        bks[i] = b;
        {
            #pragma clang fp contract(off)
            areaS[i] = (b.z - b.x) * (b.w - b.y);
        }
    }
    __syncthreads();
    for (int gw = blockIdx.x * 16 + wave; gw < TOPK * 16; gw += NB_MASK * 16) {
        int i = gw >> 4, w = gw & 15;
        int j = w * 64 + lane, jc = j < TOPK ? j : 0;
        float4 bi = bks[i], bj = bks[jc];
        bool ok;
        {
            #pragma clang fp contract(off)
            float ih = fminf(bi.z, bj.z) - fmaxf(bi.x, bj.x); ih = fmaxf(ih, 0.0f);
            float iw = fminf(bi.w, bj.w) - fmaxf(bi.y, bj.y); iw = fmaxf(iw, 0.0f);
            float inter = ih * iw;
            float denom = (areaS[i] + areaS[jc] - inter) + 1e-8f;
            ok = (j < TOPK) && (inter / denom > NMS_THR);
        }
        unsigned long long m = __ballot(ok);
        if (lane == 0) M[i * 16 + w] = m;
    }
}

// MS bank-swizzle: row stride 16 u64 = 128 B puts every lane in the same bank;
// rotating the word index by the row spreads lanes across bank-pairs.
#define MSW(i, w) ((i) * 16 + (((w) + (i)) & 15))

// ------- fused greedy scan (wave 0) + output gather (all waves), single block -------
__global__ __launch_bounds__(1024) void k_scan(const u64* __restrict__ M,
                                               const uint32_t* __restrict__ topk,
                                               const float* __restrict__ det,
                                               float* __restrict__ out) {
    __shared__ __align__(16) u64 MS[16000];       // 128 KB
    __shared__ int keeplS[MAXB];
    int tid = threadIdx.x, lane = tid & 63;
    for (int t = tid; t < TOPK * 16; t += 1024) {
        int i = t >> 4, w = t & 15;
        MS[MSW(i, w)] = M[t];
    }
    __syncthreads();
    if (tid < 64) {
        // ballot-reconstruction scan: row k of the 64x64 intra-chunk matrix equals
        // column k (IoU symmetry) = __ballot over lanes' own rows. kc chain is SALU.
        // Self-bit harmless: bit k of column-k ballot can't match kc (bit k not set yet).
        u64 keptArr[16];
        #pragma unroll
        for (int cc = 0; cc < 16; cc++) {
            int i = cc * 64 + lane;
            u64 pre = 0ull, Mic = 0ull;
            if (i < TOPK) {
                #pragma unroll
                for (int w = 0; w < cc; w++) pre |= MS[MSW(i, w)] & keptArr[w];  // final values
                Mic = MS[MSW(i, cc)];
            }
            unsigned long long pre_mask = __ballot(pre != 0ull);
            u64 kc = 0ull;
            const int lim = (cc == 15) ? (TOPK - 960) : 64;
            for (int k = 0; k < lim; k++) {
                unsigned long long b = __ballot(((Mic >> k) & 1ull) != 0ull);
                bool sup = (((pre_mask >> k) & 1ull) != 0ull) || ((b & kc) != 0ull);
                kc |= sup ? 0ull : (1ull << k);
            }
            keptArr[cc] = kc;
        }
        uint32_t pfxw[16];
        uint32_t run = 0;
        #pragma unroll
        for (int w = 0; w < 16; w++) { pfxw[w] = run; run += (uint32_t)__popcll(keptArr[w]); }
        int total = (int)run; if (total > MAXB) total = MAXB;
        for (int r = total + lane; r < MAXB; r += 64) keeplS[r] = -1;   // disjoint from rank writes
        #pragma unroll
        for (int w = 0; w < 16; w++) {
            int i = w * 64 + lane;
            if (i < TOPK) {
                u64 kw = keptArr[w];
                if ((kw >> lane) & 1ull) {
                    uint32_t rank = pfxw[w] + (uint32_t)__popcll(kw & ((1ull << lane) - 1ull));
                    if (rank < MAXB) keeplS[rank] = i;   // position in sorted top-k
                }
            }
        }
    }
    __syncthreads();
    for (int t = tid; t < MAXB * DET_DIM; t += 1024) {
        int r = t / DET_DIM, col = t - r * DET_DIM;
        int pos = keeplS[r];
        float v = 0.0f;
        if (pos >= 0) {
            uint32_t src = topk[pos];              // 300 distinct words, L2-hot
            if (src < N_ANCH) v = det[(size_t)src * DET_DIM + col];
        }
        out[t] = v;
    }
}

extern "C" void kernel_launch(void* const* d_in, const int* in_sizes, int n_in,
                              void* d_out, int out_size, void* d_ws, size_t ws_size,
                              hipStream_t stream) {
    const float4* boxes4 = (const float4*)d_in[0];
    const float4* cls4   = (const float4*)d_in[1];
    const float*  det    = (const float*)d_in[2];
    float* out = (float*)d_out;
    uint32_t* ws = (uint32_t*)d_ws;

    uint32_t* sbits = ws + OFF_SBITS;
    uint32_t* ha    = ws + OFF_HA;
    uint32_t* hb    = ws + OFF_HB;
    uint32_t* meta  = ws + OFF_META;
    u64*      cand  = (u64*)(ws + OFF_CAND);
    uint32_t* topk  = ws + OFF_TOPK;
    float4*   boxk  = (float4*)(ws + OFF_BOXK);
    u64*      M     = (u64*)(ws + OFF_MASK);

    k_scores <<<(N_ANCH + 63) / 64, 256, 0, stream>>>(cls4, sbits, ha, hb, meta);
    k_histA  <<<NB_HIST, 1024, 0, stream>>>((const uint4*)sbits, ha);
    k_histB  <<<NB_HIST, 1024, 0, stream>>>((const uint4*)sbits, ha, hb);
    k_compact<<<NB_HIST, 1024, 0, stream>>>((const uint4*)sbits, ha, hb, meta, cand);
    k_rank   <<<NB_RANK, 1024, 0, stream>>>(cand, meta, topk, boxes4, boxk);
    k_mask   <<<NB_MASK, 1024, 0, stream>>>(boxk, M);
    k_scan   <<<1, 1024, 0, stream>>>(M, topk, det, out);
}

// Round 6
// 255.618 us; speedup vs baseline: 1.0954x; 1.0954x over previous
//
#include <hip/hip_runtime.h>
#include <stdint.h>

typedef unsigned long long u64;

#define N_ANCH   300000
#define N_CLS    80
#define DET_DIM  85
#define TOPK     1000
#define MAXB     300
#define NMS_THR  0.4f
#define CAP      4096
#define N4       (N_ANCH / 4)

#define NB_HIST  80     // 80*1024 = 81920 >= 75000 uint4 -> one element per thread
#define NB_RANK  96     // 1536 waves; one wave per candidate, stride loop
#define NB_MASK  250    // 4000 waves for 16000 mask words

// ws layout (uint32 units)
#define OFF_SBITS   0          // 300000 u32
#define OFF_HA      300032     // 4096 u32 global hist A
#define OFF_HB      304128     // 4096 u32 global hist B
#define OFF_META    308224     // 64 u32: [4]=cand cnt
#define OFF_CAND    308288     // 4096 u64 = 8192 u32 (byte %8==0)
#define OFF_TOPK    316480     // 1000 u32
#define OFF_BOXK    317480     // 1000 float4 (byte %16==0)
#define OFF_MASK    321480     // 16000 u64 (byte %8==0)

// ---------------- scores = max over 80 classes (pure BW pass, ~15 us roofline) ----------------
__global__ __launch_bounds__(256) void k_scores(const float4* __restrict__ cls4,
                                                uint32_t* __restrict__ sbits,
                                                uint32_t* __restrict__ ha,
                                                uint32_t* __restrict__ hb,
                                                uint32_t* __restrict__ meta) {
    int tid = threadIdx.x;
    if (blockIdx.x == 0) {                       // zero cross-kernel state (ws poisoned)
        if (tid == 0) meta[4] = 0;
        for (int i = tid; i < 4096; i += 256) { ha[i] = 0; hb[i] = 0; }
    }
    int wave = tid >> 6, lane = tid & 63, g = lane >> 2, q = lane & 3;
    int row = blockIdx.x * 64 + wave * 16 + g;
    if (row >= N_ANCH) return;
    const float4* rp = cls4 + (size_t)row * 20;  // 80 floats = 20 float4
    float m = -1.0f;
    #pragma unroll
    for (int k = 0; k < 5; k++) {
        float4 v = rp[q + k * 4];
        m = fmaxf(m, fmaxf(fmaxf(v.x, v.y), fmaxf(v.z, v.w)));
    }
    m = fmaxf(m, __shfl_xor(m, 1));
    m = fmaxf(m, __shfl_xor(m, 2));
    if (q == 0) sbits[row] = __float_as_uint(m); // scores >= 0: bit order == value order
}

// ballot-aggregated LDS histogram add (level-A distribution is degenerate:
// ~99% of maxes land in a handful of bits[31:20] bins -> ~1 atomic per wave).
__device__ __forceinline__ void agg_add(uint32_t* h, uint32_t bin, bool valid) {
    int lane = threadIdx.x & 63;
    bool done = !valid;
    while (true) {
        unsigned long long rem = __ballot(!done);
        if (rem == 0ull) break;
        int leader = __ffsll((long long)rem) - 1;
        uint32_t lbin = __shfl(bin, leader);
        bool mine = (!done) && (bin == lbin);
        unsigned long long grp = __ballot(mine);
        if (lane == leader) atomicAdd(&h[lbin], (uint32_t)__popcll(grp));
        done = done || mine;
    }
}

// block-wide (1024 thr) threshold find via shfl wave-scan:
// per-thread counts c[k] for bins 4095-(tid*4+k); find bin where descending-suffix
// count crosses K. res[0]=bin, res[1]=count strictly above. Ends synced.
__device__ __forceinline__ void findthr_core(const uint32_t c[4], uint32_t* wred,
                                             uint32_t K, uint32_t* res) {
    int tid = threadIdx.x, lane = tid & 63, wave = tid >> 6;
    uint32_t s = c[0] + c[1] + c[2] + c[3];
    uint32_t x = s;
    #pragma unroll
    for (int off = 1; off < 64; off <<= 1) {
        uint32_t v = __shfl_up(x, off);
        if (lane >= off) x += v;
    }
    if (lane == 63) wred[wave] = x;
    __syncthreads();
    if (wave == 0) {
        uint32_t w = (lane < 16) ? wred[lane] : 0u;
        #pragma unroll
        for (int off = 1; off < 16; off <<= 1) {
            uint32_t v = __shfl_up(w, off);
            if (lane >= off) w += v;
        }
        if (lane < 16) wred[lane] = w;
    }
    __syncthreads();
    uint32_t base = (wave == 0) ? 0u : wred[wave - 1];
    uint32_t incl = base + x, excl = incl - s;
    if (excl < K && incl >= K) {                 // exactly one thread matches
        uint32_t run = excl;
        #pragma unroll
        for (int k = 0; k < 4; k++) {
            uint32_t nr = run + c[k];
            if (run < K && nr >= K) { res[0] = 4095 - (tid * 4 + k); res[1] = run; }
            run = nr;
        }
    }
    __syncthreads();
}

// helper: load the 4 descending bins for this thread as one uint4
__device__ __forceinline__ void load_bins(const uint32_t* __restrict__ hist, uint32_t c[4]) {
    uint4 q = ((const uint4*)hist)[1023 - threadIdx.x];
    c[0] = q.w; c[1] = q.z; c[2] = q.y; c[3] = q.x;
}

// ---------------- level-A histogram (bits[31:20]) -> global ha, 1 elem/thread ----------------
__global__ __launch_bounds__(1024) void k_histA(const uint4* __restrict__ sb4,
                                                uint32_t* __restrict__ ha) {
    __shared__ uint32_t h[4096];
    int tid = threadIdx.x;
    for (int i = tid; i < 4096; i += 1024) h[i] = 0;
    __syncthreads();
    int t4 = blockIdx.x * 1024 + tid;
    bool v = t4 < N4;
    uint4 sv = v ? sb4[t4] : make_uint4(0, 0, 0, 0);
    agg_add(h, sv.x >> 20, v);
    agg_add(h, sv.y >> 20, v);
    agg_add(h, sv.z >> 20, v);
    agg_add(h, sv.w >> 20, v);
    __syncthreads();
    // flush: thread-distinct bins within a block -> contention only across 80 blocks
    for (int i = tid; i < 4096; i += 1024) { uint32_t c = h[i]; if (c) atomicAdd(&ha[i], c); }
}

// ------- level-B: redundant findthr(A) per block + conditioned hist on bits[19:8] -------
__global__ __launch_bounds__(1024) void k_histB(const uint4* __restrict__ sb4,
                                                const uint32_t* __restrict__ ha,
                                                uint32_t* __restrict__ hb) {
    __shared__ uint32_t h[4096];
    __shared__ uint32_t wred[16];
    __shared__ uint32_t mr[2];
    int tid = threadIdx.x;
    uint32_t c[4];
    load_bins(ha, c);
    findthr_core(c, wred, TOPK, mr);
    uint32_t binA = mr[0];
    for (int i = tid; i < 4096; i += 1024) h[i] = 0;
    __syncthreads();
    int t4 = blockIdx.x * 1024 + tid;
    if (t4 < N4) {
        uint4 sv = sb4[t4];
        if ((sv.x >> 20) == binA) atomicAdd(&h[(sv.x >> 8) & 0xFFFu], 1u);
        if ((sv.y >> 20) == binA) atomicAdd(&h[(sv.y >> 8) & 0xFFFu], 1u);
        if ((sv.z >> 20) == binA) atomicAdd(&h[(sv.z >> 8) & 0xFFFu], 1u);
        if ((sv.w >> 20) == binA) atomicAdd(&h[(sv.w >> 8) & 0xFFFu], 1u);
    }
    __syncthreads();
    for (int i = tid; i < 4096; i += 1024) { uint32_t v = h[i]; if (v) atomicAdd(&hb[i], v); }
}

// ------- compact: redundant findthr(A)+findthr(B), single-pass ballot compact -------
__global__ __launch_bounds__(1024) void k_compact(const uint4* __restrict__ sb4,
                                                  const uint32_t* __restrict__ ha,
                                                  const uint32_t* __restrict__ hb,
                                                  uint32_t* __restrict__ meta,
                                                  u64* __restrict__ cand) {
    __shared__ uint32_t wred[16];
    __shared__ uint32_t mr[2];
    int tid = threadIdx.x, lane = tid & 63;
    uint32_t c[4];
    load_bins(ha, c);
    findthr_core(c, wred, TOPK, mr);
    uint32_t binA = mr[0], GA = mr[1];
    load_bins(hb, c);
    findthr_core(c, wred, TOPK - GA, mr);
    uint32_t T24 = (binA << 12) | mr[0];
    int t4 = blockIdx.x * 1024 + tid;
    bool v = t4 < N4;
    uint4 sv = v ? sb4[t4] : make_uint4(0, 0, 0, 0);
    uint32_t sl[4] = {sv.x, sv.y, sv.z, sv.w};
    #pragma unroll
    for (int s = 0; s < 4; s++) {
        uint32_t sb = sl[s];
        bool m = v && ((sb >> 8) >= T24);
        unsigned long long b = __ballot(m);
        if (b) {                                  // wave-uniform; cand order irrelevant
            int leader = __ffsll((long long)b) - 1;
            uint32_t base2 = 0;
            if (lane == leader) base2 = atomicAdd(&meta[4], (uint32_t)__popcll(b));
            base2 = __shfl(base2, leader);
            if (m) {
                uint32_t p = base2 + (uint32_t)__popcll(b & ((1ull << lane) - 1ull));
                uint32_t idx = (uint32_t)(t4 * 4 + s);
                if (p < CAP) cand[p] = ((u64)sb << 32) | (uint32_t)(~idx);
            }
        }
    }
}

// ------- exact rank: LDS-staged candidates, ONE WAVE per candidate (lane-parallel) -------
__global__ __launch_bounds__(1024) void k_rank(const u64* __restrict__ cand,
                                               const uint32_t* __restrict__ meta,
                                               uint32_t* __restrict__ topk,
                                               const float4* __restrict__ boxes4,
                                               float4* __restrict__ boxk) {
    __shared__ u64 candS[CAP];
    int tid = threadIdx.x, wave = tid >> 6, lane = tid & 63;
    uint32_t C = meta[4]; if (C > CAP) C = CAP;
    uint32_t Cpad = (C + 63u) & ~63u;
    for (uint32_t t = tid; t < Cpad; t += 1024) candS[t] = (t < C) ? cand[t] : 0ull;
    __syncthreads();
    for (uint32_t i = (uint32_t)(blockIdx.x * 16 + wave); i < C; i += NB_RANK * 16) {
        u64 my = candS[i];
        uint32_t r = 0;
        for (uint32_t j0 = 0; j0 < Cpad; j0 += 64)
            r += (uint32_t)__popcll(__ballot(candS[j0 + lane] > my));  // 0-pad never > my
        if (r < TOPK && lane == 0) {              // keys unique -> all ranks 0..999 hit once
            uint32_t idx = ~(uint32_t)(my & 0xFFFFFFFFull);
            if (idx < N_ANCH) { topk[r] = idx; boxk[r] = boxes4[idx]; }
        }
    }
}

// ------- suppression bitmask M[i][w]: boxes + areas staged in LDS -------
__global__ __launch_bounds__(1024) void k_mask(const float4* __restrict__ boxk,
                                               u64* __restrict__ M) {
    __shared__ float4 bks[TOPK];
    __shared__ float areaS[TOPK];
    int tid = threadIdx.x, wave = tid >> 6, lane = tid & 63;
    for (int i = tid; i < TOPK; i += 1024) {
        float4 b = boxk[i];
        bks[i] = b;
        {
            #pragma clang fp contract(off)
            areaS[i] = (b.z - b.x) * (b.w - b.y);
        }
    }
    __syncthreads();
    for (int gw = blockIdx.x * 16 + wave; gw < TOPK * 16; gw += NB_MASK * 16) {
        int i = gw >> 4, w = gw & 15;
        int j = w * 64 + lane, jc = j < TOPK ? j : 0;
        float4 bi = bks[i], bj = bks[jc];
        bool ok;
        {
            #pragma clang fp contract(off)
            float ih = fminf(bi.z, bj.z) - fmaxf(bi.x, bj.x); ih = fmaxf(ih, 0.0f);
            float iw = fminf(bi.w, bj.w) - fmaxf(bi.y, bj.y); iw = fmaxf(iw, 0.0f);
            float inter = ih * iw;
            float denom = (areaS[i] + areaS[jc] - inter) + 1e-8f;
            ok = (j < TOPK) && (inter / denom > NMS_THR);
        }
        unsigned long long m = __ballot(ok);
        if (lane == 0) M[i * 16 + w] = m;
    }
}

// ------- greedy NMS via exact Jacobi fixed-point + output gather, single block -------
// keep* is the unique fixpoint of F(keep)[i] = !any(j<i: keep[j] & M[i][j]).
// Iterating from all-ones, x_t[i] == keep*[i] for every i whose longest suppression
// chain is < t (induction on chain length), so convergence (x_{t+1}==x_t) implies
// x == keep* EXACTLY. Each thread owns row i = tid, prefix-masked in registers;
// the keep bitmask (16 u64) lives in LDS and is rebuilt via one ballot per wave.
__global__ __launch_bounds__(1024) void k_scan(const u64* __restrict__ M,
                                               const uint32_t* __restrict__ topk,
                                               const float* __restrict__ det,
                                               float* __restrict__ out) {
    __shared__ u64 kbufA[16], kbufB[16];
    __shared__ uint32_t chgF[16];
    __shared__ int keeplS[MAXB];
    const int tid = threadIdx.x, wave = tid >> 6, lane = tid & 63;
    const bool vr = tid < TOPK;

    // row i = tid, strict prefix mask (j < i); statically indexed -> stays in VGPRs
    u64 Mpre[16];
    #pragma unroll
    for (int w = 0; w < 16; w++) {
        u64 row = vr ? M[(size_t)tid * 16 + w] : 0ull;
        u64 pm = (w < wave) ? ~0ull : ((w == wave) ? ((1ull << lane) - 1ull) : 0ull);
        Mpre[w] = row & pm;
    }
    if (tid < 15) kbufA[tid] = ~0ull;
    if (tid == 15) kbufA[15] = (1ull << (TOPK - 960)) - 1ull;   // only real candidates
    __syncthreads();

    u64* cur = kbufA;
    u64* nxt = kbufB;
    for (int it = 0; it < TOPK + 2; ++it) {       // cap is defensive; converges at depth+2
        u64 sup = 0ull;
        #pragma unroll
        for (int w = 0; w < 16; w++) sup |= Mpre[w] & cur[w];   // broadcast LDS reads
        bool nk = vr && (sup == 0ull);
        u64 bal = __ballot(nk);
        if (lane == 0) { nxt[wave] = bal; chgF[wave] = (bal != cur[wave]) ? 1u : 0u; }
        __syncthreads();                          // writes visible
        uint32_t any = 0;
        #pragma unroll
        for (int w = 0; w < 16; w++) any |= chgF[w];
        __syncthreads();                          // chgF reads done before next writes
        u64* t = cur; cur = nxt; nxt = t;
        if (!any) break;                          // block-uniform
    }

    // cur == greedy keep mask: rank kept rows, publish first MAXB
    u64 kw = cur[wave];
    uint32_t pfx = 0;
    #pragma unroll
    for (int w = 0; w < 16; w++) {
        uint32_t p = (uint32_t)__popcll(cur[w]);
        if (w < wave) pfx += p;
    }
    if (tid < MAXB) keeplS[tid] = -1;
    __syncthreads();
    if (vr && ((kw >> lane) & 1ull)) {
        uint32_t rank = pfx + (uint32_t)__popcll(kw & ((1ull << lane) - 1ull));
        if (rank < MAXB) keeplS[rank] = tid;      // position in sorted top-k
    }
    __syncthreads();
    for (int t = tid; t < MAXB * DET_DIM; t += 1024) {
        int r = t / DET_DIM, col = t - r * DET_DIM;
        int pos = keeplS[r];
        float v = 0.0f;
        if (pos >= 0) {
            uint32_t src = topk[pos];             // 300 distinct words, L2-hot
            if (src < N_ANCH) v = det[(size_t)src * DET_DIM + col];
        }
        out[t] = v;
    }
}

extern "C" void kernel_launch(void* const* d_in, const int* in_sizes, int n_in,
                              void* d_out, int out_size, void* d_ws, size_t ws_size,
                              hipStream_t stream) {
    const float4* boxes4 = (const float4*)d_in[0];
    const float4* cls4   = (const float4*)d_in[1];
    const float*  det    = (const float*)d_in[2];
    float* out = (float*)d_out;
    uint32_t* ws = (uint32_t*)d_ws;

    uint32_t* sbits = ws + OFF_SBITS;
    uint32_t* ha    = ws + OFF_HA;
    uint32_t* hb    = ws + OFF_HB;
    uint32_t* meta  = ws + OFF_META;
    u64*      cand  = (u64*)(ws + OFF_CAND);
    uint32_t* topk  = ws + OFF_TOPK;
    float4*   boxk  = (float4*)(ws + OFF_BOXK);
    u64*      M     = (u64*)(ws + OFF_MASK);

    k_scores <<<(N_ANCH + 63) / 64, 256, 0, stream>>>(cls4, sbits, ha, hb, meta);
    k_histA  <<<NB_HIST, 1024, 0, stream>>>((const uint4*)sbits, ha);
    k_histB  <<<NB_HIST, 1024, 0, stream>>>((const uint4*)sbits, ha, hb);
    k_compact<<<NB_HIST, 1024, 0, stream>>>((const uint4*)sbits, ha, hb, meta, cand);
    k_rank   <<<NB_RANK, 1024, 0, stream>>>(cand, meta, topk, boxes4, boxk);
    k_mask   <<<NB_MASK, 1024, 0, stream>>>(boxk, M);
    k_scan   <<<1, 1024, 0, stream>>>(M, topk, det, out);
}

// Round 7
// 242.080 us; speedup vs baseline: 1.1566x; 1.0559x over previous
//
#include <hip/hip_runtime.h>
#include <stdint.h>

typedef unsigned long long u64;

#define N_ANCH   300000
#define N_CLS    80
#define DET_DIM  85
#define TOPK     1000
#define MAXB     300
#define NMS_THR  0.4f
#define CAP      4096
#define NBH      64                              // fused-select blocks; 128KB LDS -> 1/CU, 64<<256 CUs
#define N4       (N_ANCH / 4)
#define ITH      ((N4 + NBH*1024 - 1) / (NBH*1024))

// ws layout (uint32 units)
#define OFF_SBITS   0          // 300000 u32
#define OFF_HA      300032     // 4096 u32 global hist A
#define OFF_HB      304128     // 4096 u32 global hist B
#define OFF_META    308224     // 64 u32: [4]=cand cnt [8]=grid barrier
#define OFF_CAND    308288     // 4096 u64 = 8192 u32 (byte %8==0)
#define OFF_TOPK    316480     // 1000 u32
#define OFF_BOXK    317480     // 1000 float4 (byte %16==0)
#define OFF_MASK    321480     // 16000 u64 (byte %8==0)

// ---------- L2-bypass (MALL-coherent) accessors: relaxed agent-scope atomics ----------
// Agent-scope atomics execute at the memory-side coherence point; relaxed ordering
// emits no cache-maintenance fences — per-XCD L2s stay warm. (R3-verified.)
__device__ __forceinline__ uint32_t ld_b32(const uint32_t* p) {
    return __hip_atomic_load(p, __ATOMIC_RELAXED, __HIP_MEMORY_SCOPE_AGENT);
}
__device__ __forceinline__ u64 ld_b64(const u64* p) {
    return __hip_atomic_load(p, __ATOMIC_RELAXED, __HIP_MEMORY_SCOPE_AGENT);
}
__device__ __forceinline__ void st_b32(uint32_t* p, uint32_t v) {
    __hip_atomic_store(p, v, __ATOMIC_RELAXED, __HIP_MEMORY_SCOPE_AGENT);
}
__device__ __forceinline__ void st_b64(u64* p, u64 v) {
    __hip_atomic_store(p, v, __ATOMIC_RELAXED, __HIP_MEMORY_SCOPE_AGENT);
}
__device__ __forceinline__ void st_f4(float4* p, float4 v) {
    union { float4 f; u64 u[2]; } cv; cv.f = v;
    u64* q = (u64*)p;
    st_b64(q, cv.u[0]); st_b64(q + 1, cv.u[1]);
}
__device__ __forceinline__ float4 ld_f4(const float4* p) {
    union { float4 f; u64 u[2]; } cv;
    const u64* q = (const u64*)p;
    cv.u[0] = ld_b64(q); cv.u[1] = ld_b64(q + 1);
    return cv.f;
}

// ---------- fence-free grid barrier (NBH co-resident blocks, monotone counter) ----------
__device__ __forceinline__ void gb_arrive(uint32_t* bar) {
    __syncthreads();
    if (threadIdx.x == 0)
        __hip_atomic_fetch_add(bar, 1u, __ATOMIC_RELAXED, __HIP_MEMORY_SCOPE_AGENT);
}
__device__ __forceinline__ void gb_wait(uint32_t* bar, uint32_t target) {
    if (threadIdx.x == 0) {
        while (__hip_atomic_load(bar, __ATOMIC_RELAXED, __HIP_MEMORY_SCOPE_AGENT) < target)
            __builtin_amdgcn_s_sleep(1);
    }
    __syncthreads();
}

// ---------------- scores = max over 80 classes (pure BW pass, full grid) ----------------
__global__ __launch_bounds__(256) void k_scores(const float4* __restrict__ cls4,
                                                uint32_t* __restrict__ sbits,
                                                uint32_t* __restrict__ ha,
                                                uint32_t* __restrict__ hb,
                                                uint32_t* __restrict__ meta) {
    int tid = threadIdx.x;
    if (blockIdx.x == 0) {                       // zero cross-block state (ws poisoned)
        if (tid == 0) { meta[4] = 0; meta[8] = 0; }
        for (int i = tid; i < 4096; i += 256) { ha[i] = 0; hb[i] = 0; }
    }
    int wave = tid >> 6, lane = tid & 63, g = lane >> 2, q = lane & 3;
    int row = blockIdx.x * 64 + wave * 16 + g;
    if (row >= N_ANCH) return;
    const float4* rp = cls4 + (size_t)row * 20;  // 80 floats = 20 float4
    float m = -1.0f;
    #pragma unroll
    for (int k = 0; k < 5; k++) {
        float4 v = rp[q + k * 4];
        m = fmaxf(m, fmaxf(fmaxf(v.x, v.y), fmaxf(v.z, v.w)));
    }
    m = fmaxf(m, __shfl_xor(m, 1));
    m = fmaxf(m, __shfl_xor(m, 2));
    if (q == 0) sbits[row] = __float_as_uint(m); // scores >= 0: bit order == value order
}

// ballot-aggregated LDS histogram add (level-A distribution is degenerate:
// ~99% of maxes land in a handful of bits[31:20] bins -> ~1 atomic per wave).
__device__ __forceinline__ void agg_add(uint32_t* h, uint32_t bin, bool valid) {
    int lane = threadIdx.x & 63;
    bool done = !valid;
    while (true) {
        unsigned long long rem = __ballot(!done);
        if (rem == 0ull) break;
        int leader = __ffsll((long long)rem) - 1;
        uint32_t lbin = __shfl(bin, leader);
        bool mine = (!done) && (bin == lbin);
        unsigned long long grp = __ballot(mine);
        if (lane == leader) atomicAdd(&h[lbin], (uint32_t)__popcll(grp));
        done = done || mine;
    }
}

// block-wide (1024 thr) threshold find via shfl wave-scan. Ends synced.
__device__ __forceinline__ void findthr_core(const uint32_t c[4], uint32_t* wred,
                                             uint32_t K, uint32_t* res) {
    int tid = threadIdx.x, lane = tid & 63, wave = tid >> 6;
    uint32_t s = c[0] + c[1] + c[2] + c[3];
    uint32_t x = s;
    #pragma unroll
    for (int off = 1; off < 64; off <<= 1) {
        uint32_t v = __shfl_up(x, off);
        if (lane >= off) x += v;
    }
    if (lane == 63) wred[wave] = x;
    __syncthreads();
    if (wave == 0) {
        uint32_t w = (lane < 16) ? wred[lane] : 0u;
        #pragma unroll
        for (int off = 1; off < 16; off <<= 1) {
            uint32_t v = __shfl_up(w, off);
            if (lane >= off) w += v;
        }
        if (lane < 16) wred[lane] = w;
    }
    __syncthreads();
    uint32_t base = (wave == 0) ? 0u : wred[wave - 1];
    uint32_t incl = base + x, excl = incl - s;
    if (excl < K && incl >= K) {                 // exactly one thread matches
        uint32_t run = excl;
        #pragma unroll
        for (int k = 0; k < 4; k++) {
            uint32_t nr = run + c[k];
            if (run < K && nr >= K) { res[0] = 4095 - (tid * 4 + k); res[1] = run; }
            run = nr;
        }
    }
    __syncthreads();
}

// =============== fused select: histA -> histB -> compact -> rank -> mask -> nms ===============
__global__ __launch_bounds__(1024) void k_select(const uint4* __restrict__ sb4,
                                                 uint32_t* __restrict__ ha,
                                                 uint32_t* __restrict__ hb,
                                                 uint32_t* __restrict__ meta,
                                                 u64* __restrict__ cand,
                                                 uint32_t* __restrict__ topk,
                                                 const float4* __restrict__ boxes4,
                                                 float4* __restrict__ boxk,
                                                 u64* __restrict__ M,
                                                 const float* __restrict__ det,
                                                 float* __restrict__ out) {
    // LDS arena, phase-aliased: P1-P3 h[4096] u32 | P4 candS[4096] u64 | P5 bks+areaS
    __shared__ __align__(16) u64 big[4096];
    __shared__ uint32_t wred[16];
    __shared__ uint32_t mr[2];
    __shared__ u64 kbufA[16], kbufB[16];
    __shared__ uint32_t chgF[16];
    __shared__ int keeplS[MAXB];

    const int tid = threadIdx.x, wave = tid >> 6, lane = tid & 63;
    const int blk = blockIdx.x;
    uint32_t* bar = &meta[8];
    uint32_t* h = (uint32_t*)big;

    // ===== P1: partitioned level-A histogram (bits[31:20]) -> global ha =====
    for (int i = tid; i < 4096; i += 1024) h[i] = 0;
    __syncthreads();
    for (int it = 0; it < ITH; it++) {
        int t4 = (it * NBH + blk) * 1024 + tid;
        bool v = t4 < N4;
        uint4 sv = v ? sb4[t4] : make_uint4(0, 0, 0, 0);
        agg_add(h, sv.x >> 20, v);
        agg_add(h, sv.y >> 20, v);
        agg_add(h, sv.z >> 20, v);
        agg_add(h, sv.w >> 20, v);
    }
    __syncthreads();
    for (int i = tid; i < 4096; i += 1024) { uint32_t v = h[i]; if (v) atomicAdd(&ha[i], v); }
    gb_arrive(bar); gb_wait(bar, NBH * 1);

    // ===== P2: findthr(A) (redundant per block, bypass reads) + conditioned B-hist =====
    uint32_t c[4];
    {
        uint32_t* base = ha + 4u * (1023u - (uint32_t)tid);
        c[0] = ld_b32(base + 3); c[1] = ld_b32(base + 2);
        c[2] = ld_b32(base + 1); c[3] = ld_b32(base + 0);
    }
    findthr_core(c, wred, TOPK, mr);
    const uint32_t binA = mr[0], GA = mr[1];
    for (int i = tid; i < 4096; i += 1024) h[i] = 0;
    __syncthreads();
    for (int it = 0; it < ITH; it++) {
        int t4 = (it * NBH + blk) * 1024 + tid;
        if (t4 < N4) {
            uint4 sv = sb4[t4];
            if ((sv.x >> 20) == binA) atomicAdd(&h[(sv.x >> 8) & 0xFFFu], 1u);
            if ((sv.y >> 20) == binA) atomicAdd(&h[(sv.y >> 8) & 0xFFFu], 1u);
            if ((sv.z >> 20) == binA) atomicAdd(&h[(sv.z >> 8) & 0xFFFu], 1u);
            if ((sv.w >> 20) == binA) atomicAdd(&h[(sv.w >> 8) & 0xFFFu], 1u);
        }
    }
    __syncthreads();
    for (int i = tid; i < 4096; i += 1024) { uint32_t v = h[i]; if (v) atomicAdd(&hb[i], v); }
    gb_arrive(bar); gb_wait(bar, NBH * 2);

    // ===== P3: findthr(B) + single-pass compact (per-wave leader atomic) =====
    {
        uint32_t* base = hb + 4u * (1023u - (uint32_t)tid);
        c[0] = ld_b32(base + 3); c[1] = ld_b32(base + 2);
        c[2] = ld_b32(base + 1); c[3] = ld_b32(base + 0);
    }
    findthr_core(c, wred, TOPK - GA, mr);
    const uint32_t T24 = (binA << 12) | mr[0];
    for (int it = 0; it < ITH; it++) {
        int t4 = (it * NBH + blk) * 1024 + tid;
        bool v = t4 < N4;
        uint4 sv = v ? sb4[t4] : make_uint4(0, 0, 0, 0);
        uint32_t sl[4] = {sv.x, sv.y, sv.z, sv.w};
        #pragma unroll
        for (int s = 0; s < 4; s++) {
            uint32_t sb = sl[s];
            bool m = v && ((sb >> 8) >= T24);
            unsigned long long b = __ballot(m);
            if (b) {                              // wave-uniform; cand order irrelevant
                int leader = __ffsll((long long)b) - 1;
                uint32_t base2 = 0;
                if (lane == leader) base2 = atomicAdd(&meta[4], (uint32_t)__popcll(b));
                base2 = __shfl(base2, leader);
                if (m) {
                    uint32_t p = base2 + (uint32_t)__popcll(b & ((1ull << lane) - 1ull));
                    uint32_t idx = (uint32_t)(t4 * 4 + s);
                    if (p < CAP) st_b64(&cand[p], ((u64)sb << 32) | (uint32_t)(~idx));
                }
            }
        }
    }
    gb_arrive(bar); gb_wait(bar, NBH * 3);

    // ===== P4: exact rank — LDS-staged candidates, one wave per candidate =====
    u64* candS = big;
    uint32_t C = ld_b32(&meta[4]); if (C > CAP) C = CAP;
    uint32_t Cpad = (C + 63u) & ~63u;
    for (uint32_t t = tid; t < Cpad; t += 1024) candS[t] = (t < C) ? ld_b64(&cand[t]) : 0ull;
    __syncthreads();
    for (uint32_t i = (uint32_t)(blk * 16 + wave); i < C; i += NBH * 16) {
        u64 my = candS[i];
        uint32_t r = 0;
        for (uint32_t j0 = 0; j0 < Cpad; j0 += 64)
            r += (uint32_t)__popcll(__ballot(candS[j0 + lane] > my));  // 0-pad never > my
        if (r < TOPK && lane == 0) {              // keys unique -> all ranks 0..999 hit once
            uint32_t idx = ~(uint32_t)(my & 0xFFFFFFFFull);
            if (idx < N_ANCH) { st_b32(&topk[r], idx); st_f4(&boxk[r], boxes4[idx]); }
        }
    }
    gb_arrive(bar); gb_wait(bar, NBH * 4);

    // ===== P5: suppression bitmask M[i][w], boxes + areas staged in LDS =====
    float4* bks  = (float4*)big;                  // 16000 B
    float* areaS = (float*)((char*)big + 16000);  // 4000 B
    for (int i = tid; i < TOPK; i += 1024) {
        float4 b = ld_f4(&boxk[i]);
        bks[i] = b;
        {
            #pragma clang fp contract(off)
            areaS[i] = (b.z - b.x) * (b.w - b.y);
        }
    }
    __syncthreads();
    for (int gw = blk * 16 + wave; gw < TOPK * 16; gw += NBH * 16) {
        int i = gw >> 4, w = gw & 15;
        int j = w * 64 + lane, jc = j < TOPK ? j : 0;
        float4 bi = bks[i], bj = bks[jc];
        bool ok;
        {
            #pragma clang fp contract(off)
            float ih = fminf(bi.z, bj.z) - fmaxf(bi.x, bj.x); ih = fmaxf(ih, 0.0f);
            float iw = fminf(bi.w, bj.w) - fmaxf(bi.y, bj.y); iw = fmaxf(iw, 0.0f);
            float inter = ih * iw;
            float denom = (areaS[i] + areaS[jc] - inter) + 1e-8f;
            ok = (j < TOPK) && (inter / denom > NMS_THR);
        }
        unsigned long long m = __ballot(ok);
        if (lane == 0) st_b64(&M[i * 16 + w], m);
    }
    gb_arrive(bar); gb_wait(bar, NBH * 5);

    // ===== P6: greedy NMS via exact Jacobi fixed-point (every block, block-local) =====
    // keep* is the unique fixpoint of F(keep)[i] = !any(j<i: keep[j] & M[i][j]);
    // iterating from all-ones converges to it exactly (chain-length induction).
    // Thread tid owns row tid, prefix-masked in registers (statically indexed).
    const bool vr = tid < TOPK;
    u64 Mpre[16];
    #pragma unroll
    for (int w = 0; w < 16; w++) {
        u64 row = vr ? ld_b64(&M[(size_t)tid * 16 + w]) : 0ull;
        u64 pm = (w < wave) ? ~0ull : ((w == wave) ? ((1ull << lane) - 1ull) : 0ull);
        Mpre[w] = row & pm;
    }
    if (tid < 15) kbufA[tid] = ~0ull;
    if (tid == 15) kbufA[15] = (1ull << (TOPK - 960)) - 1ull;   // only real candidates
    __syncthreads();

    u64* cur = kbufA;
    u64* nxt = kbufB;
    for (int it = 0; it < TOPK + 2; ++it) {       // cap defensive; converges at depth+2
        u64 sup = 0ull;
        #pragma unroll
        for (int w = 0; w < 16; w++) sup |= Mpre[w] & cur[w];   // broadcast LDS reads
        bool nk = vr && (sup == 0ull);
        u64 bal = __ballot(nk);
        if (lane == 0) { nxt[wave] = bal; chgF[wave] = (bal != cur[wave]) ? 1u : 0u; }
        __syncthreads();                          // writes visible
        uint32_t any = 0;
        #pragma unroll
        for (int w = 0; w < 16; w++) any |= chgF[w];
        __syncthreads();                          // chgF reads done before next writes
        u64* t = cur; cur = nxt; nxt = t;
        if (!any) break;                          // block-uniform
    }

    u64 kw = cur[wave];
    uint32_t pfx = 0;
    #pragma unroll
    for (int w = 0; w < 16; w++) {
        uint32_t p = (uint32_t)__popcll(cur[w]);
        if (w < wave) pfx += p;
    }
    if (tid < MAXB) keeplS[tid] = -1;
    __syncthreads();
    if (vr && ((kw >> lane) & 1ull)) {
        uint32_t rank = pfx + (uint32_t)__popcll(kw & ((1ull << lane) - 1ull));
        if (rank < MAXB) keeplS[rank] = tid;      // position in sorted top-k
    }
    __syncthreads();

    // ===== P7: gather output rows (300 x 85), one slice per block =====
    int t = blk * 1024 + tid;
    if (t < MAXB * DET_DIM) {
        int r = t / DET_DIM, col = t - r * DET_DIM;
        int pos = keeplS[r];
        float v = 0.0f;
        if (pos >= 0) {
            uint32_t src = ld_b32(&topk[pos]);
            if (src < N_ANCH) v = det[(size_t)src * DET_DIM + col];
        }
        out[t] = v;
    }
}

extern "C" void kernel_launch(void* const* d_in, const int* in_sizes, int n_in,
                              void* d_out, int out_size, void* d_ws, size_t ws_size,
                              hipStream_t stream) {
    const float4* boxes4 = (const float4*)d_in[0];
    const float4* cls4   = (const float4*)d_in[1];
    const float*  det    = (const float*)d_in[2];
    float* out = (float*)d_out;
    uint32_t* ws = (uint32_t*)d_ws;

    uint32_t* sbits = ws + OFF_SBITS;
    uint32_t* ha    = ws + OFF_HA;
    uint32_t* hb    = ws + OFF_HB;
    uint32_t* meta  = ws + OFF_META;
    u64*      cand  = (u64*)(ws + OFF_CAND);
    uint32_t* topk  = ws + OFF_TOPK;
    float4*   boxk  = (float4*)(ws + OFF_BOXK);
    u64*      M     = (u64*)(ws + OFF_MASK);

    k_scores<<<(N_ANCH + 63) / 64, 256, 0, stream>>>(cls4, sbits, ha, hb, meta);
    k_select<<<NBH, 1024, 0, stream>>>((const uint4*)sbits, ha, hb, meta, cand, topk,
                                       boxes4, boxk, M, det, out);
}

// Round 8
// 240.923 us; speedup vs baseline: 1.1622x; 1.0048x over previous
//
#include <hip/hip_runtime.h>
#include <stdint.h>

typedef unsigned long long u64;

#define N_ANCH   300000
#define N_CLS    80
#define DET_DIM  85
#define TOPK     1000
#define MAXB     300
#define NMS_THR  0.4f
#define CAP      4096
#define NBH      64                              // fused-select blocks; 64 << 256 CUs
#define N4       (N_ANCH / 4)
#define ITH      ((N4 + NBH*1024 - 1) / (NBH*1024))
#define NB_NMS   25                              // 25*1024 >= 300*85 output elems

// ws layout (uint32 units)
#define OFF_SBITS   0          // 300000 u32
#define OFF_HA      300032     // 4096 u32 global hist A
#define OFF_HB      304128     // 4096 u32 global hist B
#define OFF_META    308224     // 64 u32: [4]=cand cnt [8]=grid barrier
#define OFF_CAND    308288     // 4096 u64 = 8192 u32 (byte %8==0)
#define OFF_TOPK    316480     // 1000 u32
#define OFF_BOXK    317480     // 1000 float4 (byte %16==0)
#define OFF_MASK    321480     // 16000 u64 (byte %8==0)

// ---------- L2-bypass (MALL-coherent) accessors: relaxed agent-scope atomics ----------
// Used ONLY inside k_select (cross-block, same-launch). Kernel boundaries are full
// coherence points (dispatch-end release / dispatch-start acquire) — R5/R6-verified —
// so k_nms uses plain cached loads instead.
__device__ __forceinline__ uint32_t ld_b32(const uint32_t* p) {
    return __hip_atomic_load(p, __ATOMIC_RELAXED, __HIP_MEMORY_SCOPE_AGENT);
}
__device__ __forceinline__ u64 ld_b64(const u64* p) {
    return __hip_atomic_load(p, __ATOMIC_RELAXED, __HIP_MEMORY_SCOPE_AGENT);
}
__device__ __forceinline__ void st_b32(uint32_t* p, uint32_t v) {
    __hip_atomic_store(p, v, __ATOMIC_RELAXED, __HIP_MEMORY_SCOPE_AGENT);
}
__device__ __forceinline__ void st_b64(u64* p, u64 v) {
    __hip_atomic_store(p, v, __ATOMIC_RELAXED, __HIP_MEMORY_SCOPE_AGENT);
}
__device__ __forceinline__ void st_f4(float4* p, float4 v) {
    union { float4 f; u64 u[2]; } cv; cv.f = v;
    u64* q = (u64*)p;
    st_b64(q, cv.u[0]); st_b64(q + 1, cv.u[1]);
}
__device__ __forceinline__ float4 ld_f4(const float4* p) {
    union { float4 f; u64 u[2]; } cv;
    const u64* q = (const u64*)p;
    cv.u[0] = ld_b64(q); cv.u[1] = ld_b64(q + 1);
    return cv.f;
}

// ---------- fence-free grid barrier (NBH co-resident blocks, monotone counter) ----------
__device__ __forceinline__ void gb_arrive(uint32_t* bar) {
    __syncthreads();
    if (threadIdx.x == 0)
        __hip_atomic_fetch_add(bar, 1u, __ATOMIC_RELAXED, __HIP_MEMORY_SCOPE_AGENT);
}
__device__ __forceinline__ void gb_wait(uint32_t* bar, uint32_t target) {
    if (threadIdx.x == 0) {
        while (__hip_atomic_load(bar, __ATOMIC_RELAXED, __HIP_MEMORY_SCOPE_AGENT) < target)
            __builtin_amdgcn_s_sleep(1);
    }
    __syncthreads();
}

// ---------------- scores = max over 80 classes (pure BW pass, full grid) ----------------
__global__ __launch_bounds__(256) void k_scores(const float4* __restrict__ cls4,
                                                uint32_t* __restrict__ sbits,
                                                uint32_t* __restrict__ ha,
                                                uint32_t* __restrict__ hb,
                                                uint32_t* __restrict__ meta) {
    int tid = threadIdx.x;
    if (blockIdx.x == 0) {                       // zero cross-block state (ws poisoned)
        if (tid == 0) { meta[4] = 0; meta[8] = 0; }
        for (int i = tid; i < 4096; i += 256) { ha[i] = 0; hb[i] = 0; }
    }
    int wave = tid >> 6, lane = tid & 63, g = lane >> 2, q = lane & 3;
    int row = blockIdx.x * 64 + wave * 16 + g;
    if (row >= N_ANCH) return;
    const float4* rp = cls4 + (size_t)row * 20;  // 80 floats = 20 float4
    float m = -1.0f;
    #pragma unroll
    for (int k = 0; k < 5; k++) {
        float4 v = rp[q + k * 4];
        m = fmaxf(m, fmaxf(fmaxf(v.x, v.y), fmaxf(v.z, v.w)));
    }
    m = fmaxf(m, __shfl_xor(m, 1));
    m = fmaxf(m, __shfl_xor(m, 2));
    if (q == 0) sbits[row] = __float_as_uint(m); // scores >= 0: bit order == value order
}

// ballot-aggregated LDS histogram add (level-A distribution is degenerate:
// ~99% of maxes land in a handful of bits[31:20] bins -> ~1 atomic per wave).
__device__ __forceinline__ void agg_add(uint32_t* h, uint32_t bin, bool valid) {
    int lane = threadIdx.x & 63;
    bool done = !valid;
    while (true) {
        unsigned long long rem = __ballot(!done);
        if (rem == 0ull) break;
        int leader = __ffsll((long long)rem) - 1;
        uint32_t lbin = __shfl(bin, leader);
        bool mine = (!done) && (bin == lbin);
        unsigned long long grp = __ballot(mine);
        if (lane == leader) atomicAdd(&h[lbin], (uint32_t)__popcll(grp));
        done = done || mine;
    }
}

// block-wide (1024 thr) threshold find via shfl wave-scan. Ends synced.
__device__ __forceinline__ void findthr_core(const uint32_t c[4], uint32_t* wred,
                                             uint32_t K, uint32_t* res) {
    int tid = threadIdx.x, lane = tid & 63, wave = tid >> 6;
    uint32_t s = c[0] + c[1] + c[2] + c[3];
    uint32_t x = s;
    #pragma unroll
    for (int off = 1; off < 64; off <<= 1) {
        uint32_t v = __shfl_up(x, off);
        if (lane >= off) x += v;
    }
    if (lane == 63) wred[wave] = x;
    __syncthreads();
    if (wave == 0) {
        uint32_t w = (lane < 16) ? wred[lane] : 0u;
        #pragma unroll
        for (int off = 1; off < 16; off <<= 1) {
            uint32_t v = __shfl_up(w, off);
            if (lane >= off) w += v;
        }
        if (lane < 16) wred[lane] = w;
    }
    __syncthreads();
    uint32_t base = (wave == 0) ? 0u : wred[wave - 1];
    uint32_t incl = base + x, excl = incl - s;
    if (excl < K && incl >= K) {                 // exactly one thread matches
        uint32_t run = excl;
        #pragma unroll
        for (int k = 0; k < 4; k++) {
            uint32_t nr = run + c[k];
            if (run < K && nr >= K) { res[0] = 4095 - (tid * 4 + k); res[1] = run; }
            run = nr;
        }
    }
    __syncthreads();
}

// =============== fused select: histA -> histB -> compact -> rank -> mask ===============
__global__ __launch_bounds__(1024) void k_select(const uint4* __restrict__ sb4,
                                                 uint32_t* __restrict__ ha,
                                                 uint32_t* __restrict__ hb,
                                                 uint32_t* __restrict__ meta,
                                                 u64* __restrict__ cand,
                                                 uint32_t* __restrict__ topk,
                                                 const float4* __restrict__ boxes4,
                                                 float4* __restrict__ boxk,
                                                 u64* __restrict__ M) {
    // LDS arena, phase-aliased: P1-P3 h[4096] u32 | P4 candS[4096] u64 | P5 bks+areaS
    __shared__ __align__(16) u64 big[4096];
    __shared__ uint32_t wred[16];
    __shared__ uint32_t mr[2];

    const int tid = threadIdx.x, wave = tid >> 6, lane = tid & 63;
    const int blk = blockIdx.x;
    uint32_t* bar = &meta[8];
    uint32_t* h = (uint32_t*)big;

    // ===== P1: partitioned level-A histogram (bits[31:20]) -> global ha =====
    for (int i = tid; i < 4096; i += 1024) h[i] = 0;
    __syncthreads();
    for (int it = 0; it < ITH; it++) {
        int t4 = (it * NBH + blk) * 1024 + tid;
        bool v = t4 < N4;
        uint4 sv = v ? sb4[t4] : make_uint4(0, 0, 0, 0);
        agg_add(h, sv.x >> 20, v);
        agg_add(h, sv.y >> 20, v);
        agg_add(h, sv.z >> 20, v);
        agg_add(h, sv.w >> 20, v);
    }
    __syncthreads();
    for (int i = tid; i < 4096; i += 1024) { uint32_t v = h[i]; if (v) atomicAdd(&ha[i], v); }
    gb_arrive(bar); gb_wait(bar, NBH * 1);

    // ===== P2: findthr(A) (redundant per block, bypass reads) + conditioned B-hist =====
    uint32_t c[4];
    {
        uint32_t* base = ha + 4u * (1023u - (uint32_t)tid);
        c[0] = ld_b32(base + 3); c[1] = ld_b32(base + 2);
        c[2] = ld_b32(base + 1); c[3] = ld_b32(base + 0);
    }
    findthr_core(c, wred, TOPK, mr);
    const uint32_t binA = mr[0], GA = mr[1];
    for (int i = tid; i < 4096; i += 1024) h[i] = 0;
    __syncthreads();
    for (int it = 0; it < ITH; it++) {
        int t4 = (it * NBH + blk) * 1024 + tid;
        if (t4 < N4) {
            uint4 sv = sb4[t4];
            if ((sv.x >> 20) == binA) atomicAdd(&h[(sv.x >> 8) & 0xFFFu], 1u);
            if ((sv.y >> 20) == binA) atomicAdd(&h[(sv.y >> 8) & 0xFFFu], 1u);
            if ((sv.z >> 20) == binA) atomicAdd(&h[(sv.z >> 8) & 0xFFFu], 1u);
            if ((sv.w >> 20) == binA) atomicAdd(&h[(sv.w >> 8) & 0xFFFu], 1u);
        }
    }
    __syncthreads();
    for (int i = tid; i < 4096; i += 1024) { uint32_t v = h[i]; if (v) atomicAdd(&hb[i], v); }
    gb_arrive(bar); gb_wait(bar, NBH * 2);

    // ===== P3: findthr(B) + single-pass compact (per-wave leader atomic) =====
    {
        uint32_t* base = hb + 4u * (1023u - (uint32_t)tid);
        c[0] = ld_b32(base + 3); c[1] = ld_b32(base + 2);
        c[2] = ld_b32(base + 1); c[3] = ld_b32(base + 0);
    }
    findthr_core(c, wred, TOPK - GA, mr);
    const uint32_t T24 = (binA << 12) | mr[0];
    for (int it = 0; it < ITH; it++) {
        int t4 = (it * NBH + blk) * 1024 + tid;
        bool v = t4 < N4;
        uint4 sv = v ? sb4[t4] : make_uint4(0, 0, 0, 0);
        uint32_t sl[4] = {sv.x, sv.y, sv.z, sv.w};
        #pragma unroll
        for (int s = 0; s < 4; s++) {
            uint32_t sb = sl[s];
            bool m = v && ((sb >> 8) >= T24);
            unsigned long long b = __ballot(m);
            if (b) {                              // wave-uniform; cand order irrelevant
                int leader = __ffsll((long long)b) - 1;
                uint32_t base2 = 0;
                if (lane == leader) base2 = atomicAdd(&meta[4], (uint32_t)__popcll(b));
                base2 = __shfl(base2, leader);
                if (m) {
                    uint32_t p = base2 + (uint32_t)__popcll(b & ((1ull << lane) - 1ull));
                    uint32_t idx = (uint32_t)(t4 * 4 + s);
                    if (p < CAP) st_b64(&cand[p], ((u64)sb << 32) | (uint32_t)(~idx));
                }
            }
        }
    }
    gb_arrive(bar); gb_wait(bar, NBH * 3);

    // ===== P4: exact rank — LDS-staged candidates, one wave per candidate =====
    u64* candS = big;
    uint32_t C = ld_b32(&meta[4]); if (C > CAP) C = CAP;
    uint32_t Cpad = (C + 63u) & ~63u;
    for (uint32_t t = tid; t < Cpad; t += 1024) candS[t] = (t < C) ? ld_b64(&cand[t]) : 0ull;
    __syncthreads();
    for (uint32_t i = (uint32_t)(blk * 16 + wave); i < C; i += NBH * 16) {
        u64 my = candS[i];
        uint32_t r = 0;
        for (uint32_t j0 = 0; j0 < Cpad; j0 += 64)
            r += (uint32_t)__popcll(__ballot(candS[j0 + lane] > my));  // 0-pad never > my
        if (r < TOPK && lane == 0) {              // keys unique -> all ranks 0..999 hit once
            uint32_t idx = ~(uint32_t)(my & 0xFFFFFFFFull);
            if (idx < N_ANCH) { st_b32(&topk[r], idx); st_f4(&boxk[r], boxes4[idx]); }
        }
    }
    gb_arrive(bar); gb_wait(bar, NBH * 4);

    // ===== P5: suppression bitmask M[i][w]; kernel end is the final sync =====
    float4* bks  = (float4*)big;                  // 16000 B
    float* areaS = (float*)((char*)big + 16000);  // 4000 B
    for (int i = tid; i < TOPK; i += 1024) {
        float4 b = ld_f4(&boxk[i]);
        bks[i] = b;
        {
            #pragma clang fp contract(off)
            areaS[i] = (b.z - b.x) * (b.w - b.y);
        }
    }
    __syncthreads();
    for (int gw = blk * 16 + wave; gw < TOPK * 16; gw += NBH * 16) {
        int i = gw >> 4, w = gw & 15;
        int j = w * 64 + lane, jc = j < TOPK ? j : 0;
        float4 bi = bks[i], bj = bks[jc];
        bool ok;
        {
            #pragma clang fp contract(off)
            float ih = fminf(bi.z, bj.z) - fmaxf(bi.x, bj.x); ih = fmaxf(ih, 0.0f);
            float iw = fminf(bi.w, bj.w) - fmaxf(bi.y, bj.y); iw = fmaxf(iw, 0.0f);
            float inter = ih * iw;
            float denom = (areaS[i] + areaS[jc] - inter) + 1e-8f;
            ok = (j < TOPK) && (inter / denom > NMS_THR);
        }
        unsigned long long m = __ballot(ok);
        if (lane == 0) st_b64(&M[i * 16 + w], m);
    }
}

// ------- greedy NMS via exact Jacobi fixed-point + output gather -------
// keep* is the unique fixpoint of F(keep)[i] = !any(j<i: keep[j] & M[i][j]);
// iterating from all-ones converges to it exactly (chain-length induction).
// Every block computes the (deterministic) fixpoint, then gathers one out-slice.
// Plain cached loads: kernel boundary is the coherence point.
__global__ __launch_bounds__(1024) void k_nms(const u64* __restrict__ M,
                                              const uint32_t* __restrict__ topk,
                                              const float* __restrict__ det,
                                              float* __restrict__ out) {
    __shared__ u64 kbufA[16], kbufB[16];
    __shared__ int keeplS[MAXB];
    const int tid = threadIdx.x, wave = tid >> 6, lane = tid & 63;
    const bool vr = tid < TOPK;

    u64 Mpre[16];                                 // row tid, strict prefix (j < tid)
    #pragma unroll
    for (int w = 0; w < 16; w++) {
        u64 row = vr ? M[(size_t)tid * 16 + w] : 0ull;
        u64 pm = (w < wave) ? ~0ull : ((w == wave) ? ((1ull << lane) - 1ull) : 0ull);
        Mpre[w] = row & pm;
    }
    if (tid < 15) kbufA[tid] = ~0ull;
    if (tid == 15) kbufA[15] = (1ull << (TOPK - 960)) - 1ull;   // only real candidates
    __syncthreads();

    u64* cur = kbufA;
    u64* nxt = kbufB;
    for (int it = 0; it < TOPK + 2; ++it) {       // cap defensive; converges at depth+2
        u64 sup = 0ull;
        #pragma unroll
        for (int w = 0; w < 16; w++) sup |= Mpre[w] & cur[w];   // broadcast LDS reads
        bool nk = vr && (sup == 0ull);
        u64 bal = __ballot(nk);
        if (lane == 0) nxt[wave] = bal;
        // one barrier/iter: makes nxt writes visible AND returns block-wide change flag.
        // cur-buffer reads of iter t all precede this barrier; its overwrite (as nxt)
        // happens in iter t+1 after it -> no race.
        int changed = __syncthreads_or((int)(lane == 0 && bal != cur[wave]));
        u64* t = cur; cur = nxt; nxt = t;
        if (!changed) break;                      // block-uniform
    }

    u64 kw = cur[wave];
    uint32_t pfx = 0;
    #pragma unroll
    for (int w = 0; w < 16; w++) {
        uint32_t p = (uint32_t)__popcll(cur[w]);
        if (w < wave) pfx += p;
    }
    if (tid < MAXB) keeplS[tid] = -1;
    __syncthreads();
    if (vr && ((kw >> lane) & 1ull)) {
        uint32_t rank = pfx + (uint32_t)__popcll(kw & ((1ull << lane) - 1ull));
        if (rank < MAXB) keeplS[rank] = tid;      // position in sorted top-k
    }
    __syncthreads();

    int t = blockIdx.x * 1024 + tid;              // one slice per block
    if (t < MAXB * DET_DIM) {
        int r = t / DET_DIM, col = t - r * DET_DIM;
        int pos = keeplS[r];
        float v = 0.0f;
        if (pos >= 0) {
            uint32_t src = topk[pos];
            if (src < N_ANCH) v = det[(size_t)src * DET_DIM + col];
        }
        out[t] = v;
    }
}

extern "C" void kernel_launch(void* const* d_in, const int* in_sizes, int n_in,
                              void* d_out, int out_size, void* d_ws, size_t ws_size,
                              hipStream_t stream) {
    const float4* boxes4 = (const float4*)d_in[0];
    const float4* cls4   = (const float4*)d_in[1];
    const float*  det    = (const float*)d_in[2];
    float* out = (float*)d_out;
    uint32_t* ws = (uint32_t*)d_ws;

    uint32_t* sbits = ws + OFF_SBITS;
    uint32_t* ha    = ws + OFF_HA;
    uint32_t* hb    = ws + OFF_HB;
    uint32_t* meta  = ws + OFF_META;
    u64*      cand  = (u64*)(ws + OFF_CAND);
    uint32_t* topk  = ws + OFF_TOPK;
    float4*   boxk  = (float4*)(ws + OFF_BOXK);
    u64*      M     = (u64*)(ws + OFF_MASK);

    k_scores<<<(N_ANCH + 63) / 64, 256, 0, stream>>>(cls4, sbits, ha, hb, meta);
    k_select<<<NBH, 1024, 0, stream>>>((const uint4*)sbits, ha, hb, meta, cand, topk,
                                       boxes4, boxk, M);
    k_nms   <<<NB_NMS, 1024, 0, stream>>>(M, topk, det, out);
}